// Round 13
// baseline (88.826 us; speedup 1.0000x reference)
//
#include <hip/hip_runtime.h>

// Local 8x8 window autocorrelation, stride 4.
// x: (B, C, H, W) fp32 -> out: (B, C, nH, nW, KH, KW) fp32
// out[n, dy, dx] = sum_{i,j} p[i+dy-4][j+dx-4] * p[i][j]  (zero outside window)
//
// R13: ONE LANE PER (window, dy) — 8 lanes/window, 2.17M threads.
// Rationale: R8..R12 (full window per thread + LDS staging) converged at
// ~30us: per-wave issue ~1.7K cyc of ~30K lifetime at the structural
// residency cap (~4 waves/SIMD from VGPR~110 / 8.3KB LDS per wave of
// windows). This decomposition is latency-IMMUNE instead of latency-hiding:
//  - runtime oy=dy-4 appears ONLY in load addresses (clamped + cndmask-zero
//    for invalid rows); all register indexing static -> no scratch.
//  - static j-guards trim to 48 FMA/step = 384 FMA/lane, uniform across
//    lanes -> zero divergence, zero wave imbalance.
//  - ~50 VGPR (2x ping-pong row pair + 8 acc) -> 8 waves/SIMD; ZERO LDS,
//    no syncthreads, no flush phase.
//  - stores: each lane's dy row = 32B contiguous, two back-to-back dwordx4;
//    the wave's pair covers a dense 2KB span of complete 256B window
//    regions (partial-sector writes cost 3-4.7x: R1/R4 evidence).
//  - b-row loads: 8 lanes of a window read the same address -> coalesced
//    broadcast. XCD swizzle (8464 = 8*1058, bijective) for L2 locality.

constexpr int KH = 8, KW = 8, SH = 4, SW = 4;
constexpr int B = 8, C = 64, H = 96, W = 96;
constexpr int nH = (H - KH) / SH + 1;  // 23
constexpr int nW = (W - KW) / SW + 1;  // 23
constexpr int NWIN = B * C * nH * nW;  // 270848
constexpr int TPB = 256;
constexpr int NTASK = NWIN * 8;        // 2166784 = 8464 * 256
constexpr int NBLK = NTASK / TPB;      // 8464 = 8 * 1058
constexpr int NXCD = 8;
constexpr int CPX = NBLK / NXCD;       // 1058

__global__ __launch_bounds__(TPB) void
local_autocorr_kernel(const float* __restrict__ x, float* __restrict__ out) {
    // Bijective XCD swizzle.
    const int bid = (int)blockIdx.x;
    const int blk = (bid % NXCD) * CPX + bid / NXCD;
    const int gt  = blk * TPB + (int)threadIdx.x;

    const int n  = gt >> 3;   // window
    const int dy = gt & 7;    // this lane's output row
    const int oy = dy - 4;    // runtime, address-only

    const int w  = n % nW;
    const int t2 = n / nW;
    const int h  = t2 % nH;
    const int bc = t2 / nH;   // b*C + c

    const float* xp = x + ((size_t)bc * H + (size_t)h * SH) * W + (size_t)w * SW;

    float acc[8] = {0.f, 0.f, 0.f, 0.f, 0.f, 0.f, 0.f, 0.f};

    float b0[8], a0[8], b1[8], a1[8];

#define LOADB(dst, ri)                                                                \
    {                                                                                 \
        const float4 lo_ = *reinterpret_cast<const float4*>(xp + (size_t)(ri)*W);     \
        const float4 hi_ = *reinterpret_cast<const float4*>(xp + (size_t)(ri)*W + 4); \
        dst[0]=lo_.x; dst[1]=lo_.y; dst[2]=lo_.z; dst[3]=lo_.w;                       \
        dst[4]=hi_.x; dst[5]=hi_.y; dst[6]=hi_.z; dst[7]=hi_.w;                       \
    }

    // A row (i+oy): clamped address for OOB rows, cndmask result to zero.
#define LOADA(dst, ri)                                                                \
    {                                                                                 \
        const int ra_ = (ri) + oy;                                                    \
        const bool v_ = ((unsigned)ra_ < 8u);                                         \
        const float* ap_ = xp + (size_t)(v_ ? ra_ : 0) * W;                           \
        const float4 lo_ = *reinterpret_cast<const float4*>(ap_);                     \
        const float4 hi_ = *reinterpret_cast<const float4*>(ap_ + 4);                 \
        dst[0] = v_ ? lo_.x : 0.f; dst[1] = v_ ? lo_.y : 0.f;                         \
        dst[2] = v_ ? lo_.z : 0.f; dst[3] = v_ ? lo_.w : 0.f;                         \
        dst[4] = v_ ? hi_.x : 0.f; dst[5] = v_ ? hi_.y : 0.f;                         \
        dst[6] = v_ ? hi_.z : 0.f; dst[7] = v_ ? hi_.w : 0.f;                         \
    }

    // 48 FMAs (static j-guard trim), all register indices compile-time.
#define FMABLK(bb, aa)                                                                \
    {                                                                                 \
        _Pragma("unroll")                                                             \
        for (int dx = 0; dx < 8; ++dx) {                                              \
            const int OX = dx - 4;                                                    \
            _Pragma("unroll")                                                         \
            for (int j = 0; j < 8; ++j) {                                             \
                if (j + OX < 0 || j + OX >= 8) continue; /* static DCE */             \
                acc[dx] = fmaf(aa[j + OX], bb[j], acc[dx]);                           \
            }                                                                         \
        }                                                                             \
    }

    LOADB(b0, 0) LOADA(a0, 0)
#pragma unroll
    for (int ii = 0; ii < 4; ++ii) {
        const int i = 2 * ii;  // compile-time after unroll
        // prefetch i+1 into ping-pong buffer 1, compute i from buffer 0
        LOADB(b1, i + 1) LOADA(a1, i + 1)
        FMABLK(b0, a0)
        __builtin_amdgcn_sched_barrier(0);  // contain liveness/hoisting
        if (i + 2 < 8) { LOADB(b0, i + 2) LOADA(a0, i + 2) }
        FMABLK(b1, a1)
        __builtin_amdgcn_sched_barrier(0);
    }

#undef LOADB
#undef LOADA
#undef FMABLK

    // Store this lane's dy row: 32B contiguous, two back-to-back dwordx4.
    // Wave's pair of stores covers a dense 2KB span (8 full 256B windows).
    float* op = out + (size_t)n * 64 + dy * 8;
    *reinterpret_cast<float4*>(op)     = make_float4(acc[0], acc[1], acc[2], acc[3]);
    *reinterpret_cast<float4*>(op + 4) = make_float4(acc[4], acc[5], acc[6], acc[7]);
}

extern "C" void kernel_launch(void* const* d_in, const int* in_sizes, int n_in,
                              void* d_out, int out_size, void* d_ws, size_t ws_size,
                              hipStream_t stream) {
    const float* x = (const float*)d_in[0];
    float* out = (float*)d_out;

    local_autocorr_kernel<<<NBLK, TPB, 0, stream>>>(x, out);
}

// Round 14
// 44.686 us; speedup vs baseline: 1.9878x; 1.9878x over previous
//
#include <hip/hip_runtime.h>

// Local 8x8 window autocorrelation, stride 4.
// x: (B, C, H, W) fp32 -> out: (B, C, nH, nW, KH, KW) fp32
// out[n, dy, dx] = sum_{i,j} p[i+dy-4][j+dx-4] * p[i][j]  (zero outside window)
//
// R14 = R12 (best, 29.6us) + residency push. R13 (lane-per-(window,dy))
// refuted the scatter direction: 2x FMA + 3x VALU overhead, 88us.
// R12's limiter: ~2K cyc issue per ~30K cyc wave lifetime at ~4 waves/SIMD
// residency (VGPR ~110, LDS 16.6KB). Fill kernels prove write path has 3x
// headroom -> remedy = residency, never yet raised on the lean structure.
// Changes (numerics identical, absmax unchanged):
//  1. role B prefetch 2->1: live rows r-4..r+1 -> ~82 live regs (A ~55).
//  2. __launch_bounds__(128,3): empirical cap model (R3: arg*TPB/64 waves/EU)
//     -> VGPR cap 512/6 = 85, forcing a 6-waves/SIMD allocation.
//     FAILURE SIGNATURE if live set misjudged: WRITE_SIZE >> 67.7MB (spill).
//  3. two-phase 32-window flush (R9/R11-proven): LDS 16.6 -> 8.3KB.
// Kept: wave-role split (A: d0,d1,c50 = 748 FMA; B: d2,d3,d4,c60,c70 = 764),
// XCD swizzle (4232 = 8*529), 1KB full-sector wave stores (partial-sector
// writes cost 3-4.7x: R1/R4; byte-exact since R6).

constexpr int KH = 8, KW = 8, SH = 4, SW = 4;
constexpr int B = 8, C = 64, H = 96, W = 96;
constexpr int nH = (H - KH) / SH + 1;  // 23
constexpr int nW = (W - KW) / SW + 1;  // 23
constexpr int NWIN = B * C * nH * nW;  // 270848 = 64 * 4232
constexpr int TPB = 128;
constexpr int WPB = 64;                // windows per block
constexpr int HALFW = 32;              // windows staged per flush phase
constexpr int OSTRIDE = 65;            // 64 floats + 1 pad
constexpr int NBLK = NWIN / WPB;       // 4232 = 8 * 529
constexpr int NXCD = 8;
constexpr int CPX = NBLK / NXCD;       // 529

__global__ __launch_bounds__(TPB, 3) void
local_autocorr_kernel(const float* __restrict__ x, float* __restrict__ out) {
    __shared__ float lds[HALFW * OSTRIDE];  // 8320 B

    const int tid  = threadIdx.x;
    const int role = tid >> 6;           // wave-uniform: wave 0 = A, wave 1 = B
    const int k    = tid & 63;           // window within block

    // Bijective XCD swizzle: blocks bid%8==c form one contiguous span.
    const int bid = (int)blockIdx.x;
    const int blk = (bid % NXCD) * CPX + bid / NXCD;
    const int n = blk * WPB + k;

    const int w  = n % nW;
    const int tt = n / nW;
    const int h  = tt % nH;
    const int bc = tt / nH;  // b*C + c

    const float* xp = x + ((size_t)bc * H + (size_t)h * SH) * W + (size_t)w * SW;

#define LOADROW(dst, ri)                                                              \
    {                                                                                 \
        const float4 lo_ = *reinterpret_cast<const float4*>(xp + (size_t)(ri)*W);     \
        const float4 hi_ = *reinterpret_cast<const float4*>(xp + (size_t)(ri)*W + 4); \
        dst[0]=lo_.x; dst[1]=lo_.y; dst[2]=lo_.z; dst[3]=lo_.w;                       \
        dst[4]=hi_.x; dst[5]=hi_.y; dst[6]=hi_.z; dst[7]=hi_.w;                       \
    }

    float accD0[8], accD1[8], accD2[8], accD3[8], accD4[8];
    float c50 = 0.f, c60 = 0.f, c70 = 0.f;

    if (role == 0) {
        // ---- role A: d=0 (dy=4), d=1 (dy=3), c50. Rows r-1..r+2 live. ----
#pragma unroll
        for (int dx = 0; dx < 8; ++dx) { accD0[dx] = 0.f; accD1[dx] = 0.f; }

        float rows[8][8];
        LOADROW(rows[0], 0)
        LOADROW(rows[1], 1)
#pragma unroll
        for (int r = 0; r < 8; ++r) {
            if (r < 6) LOADROW(rows[r + 2], r + 2)
            // d = 0 -> dy = 4
#pragma unroll
            for (int dx = 0; dx < 8; ++dx) {
                const int OX = dx - 4;
#pragma unroll
                for (int j = 0; j < 8; ++j) {
                    if (j + OX < 0 || j + OX >= 8) continue;  // static DCE
                    accD0[dx] = fmaf(rows[r][j + OX], rows[r][j], accD0[dx]);
                }
            }
            // d = 1 -> dy = 3 (+ folded cell (5,0))
            if (r >= 1) {
#pragma unroll
                for (int dx = 0; dx < 8; ++dx) {
                    const int OX = dx - 4;
#pragma unroll
                    for (int j = 0; j < 8; ++j) {
                        if (j + OX < 0 || j + OX >= 8) continue;
                        accD1[dx] = fmaf(rows[r - 1][j + OX], rows[r][j], accD1[dx]);
                    }
                }
                c50 = fmaf(rows[r][0], rows[r - 1][4], c50);
                c50 = fmaf(rows[r][1], rows[r - 1][5], c50);
                c50 = fmaf(rows[r][2], rows[r - 1][6], c50);
                c50 = fmaf(rows[r][3], rows[r - 1][7], c50);
            }
            __builtin_amdgcn_sched_barrier(0);
        }
    } else {
        // ---- role B: d=2,3,4 + c60,c70. Prefetch-1: rows r-4..r+1 live. ----
#pragma unroll
        for (int dx = 0; dx < 8; ++dx) { accD2[dx] = 0.f; accD3[dx] = 0.f; accD4[dx] = 0.f; }

        float rows[8][8];
#pragma unroll
        for (int kk = 0; kk < 3; ++kk) LOADROW(rows[kk], kk)
#pragma unroll
        for (int r = 2; r < 8; ++r) {
            if (r < 7) LOADROW(rows[r + 1], r + 1)
            // d = 2 -> dy = 2 (+ folded cell (6,0))
#pragma unroll
            for (int dx = 0; dx < 8; ++dx) {
                const int OX = dx - 4;
#pragma unroll
                for (int j = 0; j < 8; ++j) {
                    if (j + OX < 0 || j + OX >= 8) continue;
                    accD2[dx] = fmaf(rows[r - 2][j + OX], rows[r][j], accD2[dx]);
                }
            }
            c60 = fmaf(rows[r][0], rows[r - 2][4], c60);
            c60 = fmaf(rows[r][1], rows[r - 2][5], c60);
            c60 = fmaf(rows[r][2], rows[r - 2][6], c60);
            c60 = fmaf(rows[r][3], rows[r - 2][7], c60);
            // d = 3 -> dy = 1 (+ folded cell (7,0))
            if (r >= 3) {
#pragma unroll
                for (int dx = 0; dx < 8; ++dx) {
                    const int OX = dx - 4;
#pragma unroll
                    for (int j = 0; j < 8; ++j) {
                        if (j + OX < 0 || j + OX >= 8) continue;
                        accD3[dx] = fmaf(rows[r - 3][j + OX], rows[r][j], accD3[dx]);
                    }
                }
                c70 = fmaf(rows[r][0], rows[r - 3][4], c70);
                c70 = fmaf(rows[r][1], rows[r - 3][5], c70);
                c70 = fmaf(rows[r][2], rows[r - 3][6], c70);
                c70 = fmaf(rows[r][3], rows[r - 3][7], c70);
            }
            // d = 4 -> dy = 0
            if (r >= 4) {
#pragma unroll
                for (int dx = 0; dx < 8; ++dx) {
                    const int OX = dx - 4;
#pragma unroll
                    for (int j = 0; j < 8; ++j) {
                        if (j + OX < 0 || j + OX >= 8) continue;
                        accD4[dx] = fmaf(rows[r - 4][j + OX], rows[r][j], accD4[dx]);
                    }
                }
            }
            __builtin_amdgcn_sched_barrier(0);
        }
    }
#undef LOADROW

    // ---- Two-phase stage + flush (8KB contiguous spans, full-sector). ----
    float* obase = out + (size_t)blk * WPB * 64;
#pragma unroll
    for (int ph = 0; ph < 2; ++ph) {
        if ((k >> 5) == ph) {
            float* slot = &lds[(k & 31) * OSTRIDE];
            if (role == 0) {
                // rows dy=3,4 + mirror row 5 ([5][dx]=accD1[8-dx], [5][0]=c50)
                *reinterpret_cast<float4*>(slot + 24) = make_float4(accD1[0], accD1[1], accD1[2], accD1[3]);
                *reinterpret_cast<float4*>(slot + 28) = make_float4(accD1[4], accD1[5], accD1[6], accD1[7]);
                *reinterpret_cast<float4*>(slot + 32) = make_float4(accD0[0], accD0[1], accD0[2], accD0[3]);
                *reinterpret_cast<float4*>(slot + 36) = make_float4(accD0[4], accD0[5], accD0[6], accD0[7]);
                *reinterpret_cast<float4*>(slot + 40) = make_float4(c50,      accD1[7], accD1[6], accD1[5]);
                *reinterpret_cast<float4*>(slot + 44) = make_float4(accD1[4], accD1[3], accD1[2], accD1[1]);
            } else {
                // rows dy=0,1,2 + mirror rows 6,7
                *reinterpret_cast<float4*>(slot + 0)  = make_float4(accD4[0], accD4[1], accD4[2], accD4[3]);
                *reinterpret_cast<float4*>(slot + 4)  = make_float4(accD4[4], accD4[5], accD4[6], accD4[7]);
                *reinterpret_cast<float4*>(slot + 8)  = make_float4(accD3[0], accD3[1], accD3[2], accD3[3]);
                *reinterpret_cast<float4*>(slot + 12) = make_float4(accD3[4], accD3[5], accD3[6], accD3[7]);
                *reinterpret_cast<float4*>(slot + 16) = make_float4(accD2[0], accD2[1], accD2[2], accD2[3]);
                *reinterpret_cast<float4*>(slot + 20) = make_float4(accD2[4], accD2[5], accD2[6], accD2[7]);
                *reinterpret_cast<float4*>(slot + 48) = make_float4(c60,      accD2[7], accD2[6], accD2[5]);
                *reinterpret_cast<float4*>(slot + 52) = make_float4(accD2[4], accD2[3], accD2[2], accD2[1]);
                *reinterpret_cast<float4*>(slot + 56) = make_float4(c70,      accD3[7], accD3[6], accD3[5]);
                *reinterpret_cast<float4*>(slot + 60) = make_float4(accD3[4], accD3[3], accD3[2], accD3[1]);
            }
        }
        __syncthreads();
        // Flush 32 windows x 16 float4 = 512 slots, 4 per thread; each wave
        // store covers 1KB contiguous (4 complete 256B window regions).
#pragma unroll
        for (int kk = 0; kk < 4; ++kk) {
            const int flat4 = tid + kk * TPB;   // 0..511
            const float4 v = *reinterpret_cast<const float4*>(
                &lds[(flat4 >> 4) * OSTRIDE + (flat4 & 15) * 4]);
            *reinterpret_cast<float4*>(obase + (size_t)ph * HALFW * 64 + flat4 * 4) = v;
        }
        __syncthreads();  // WAR: protect slab before phase 1 restages
    }
}

extern "C" void kernel_launch(void* const* d_in, const int* in_sizes, int n_in,
                              void* d_out, int out_size, void* d_ws, size_t ws_size,
                              hipStream_t stream) {
    const float* x = (const float*)d_in[0];
    float* out = (float*)d_out;

    local_autocorr_kernel<<<NBLK, TPB, 0, stream>>>(x, out);
}

// Round 15
// 32.663 us; speedup vs baseline: 2.7195x; 1.3681x over previous
//
#include <hip/hip_runtime.h>

// Local 8x8 window autocorrelation, stride 4.
// x: (B, C, H, W) fp32 -> out: (B, C, nH, nW, KH, KW) fp32
// out[n, dy, dx] = sum_{i,j} p[i+dy-4][j+dx-4] * p[i][j]  (zero outside window)
//
// R15: FOUR-wave role split, one d-group per wave, 2-4 row operand windows.
// Calibrated VGPR-cap model (R3/R14): launch_bounds(TPB,w) caps at
// 512/(w*TPB/64); R14 proved the R12 live set (~90-110) spills under 84.
// So shrink the live set structurally: a role handling offset d needs only
// a (d+1)-deep row ring; d=4 re-loads row r-4 from L1 (self-loaded 4 steps
// earlier -> hot) instead of aging 3 dead rows. All roles <= ~50 live ->
// cap 64 binds WITHOUT spill -> 8 waves/SIMD (vs R12's 4).
//   W0: d0 (dy4) + d4 (dy0)        576 FMA  cur + reloaded aux
//   W1: d1 (dy3) + c50             364 FMA  2-ring
//   W2: d2 (dy2) + c60             336 FMA  3-ring
//   W3: d3 (dy1) + c70             280 FMA  4-ring
// Staging INSIDE each role branch (accs die before merge); single-phase
// 64-window slab (16.6KB; 8 blocks/CU = 133KB <= 160KB, no LDS cap); flush
// = proven 1KB full-sector wave stores (partial-sector = 3-4.7x: R1/R4).
// Per-cell summation order identical to R12 -> absmax unchanged.
// XCD swizzle (4232 = 8*529, bijective). Zero divergence (role = wave id).

constexpr int KH = 8, KW = 8, SH = 4, SW = 4;
constexpr int B = 8, C = 64, H = 96, W = 96;
constexpr int nH = (H - KH) / SH + 1;  // 23
constexpr int nW = (W - KW) / SW + 1;  // 23
constexpr int NWIN = B * C * nH * nW;  // 270848 = 64 * 4232
constexpr int TPB = 256;
constexpr int WPB = 64;                // windows per block
constexpr int OSTRIDE = 65;            // 64 floats + 1 pad
constexpr int NBLK = NWIN / WPB;       // 4232 = 8 * 529
constexpr int NXCD = 8;
constexpr int CPX = NBLK / NXCD;       // 529

__global__ __launch_bounds__(TPB, 2) void
local_autocorr_kernel(const float* __restrict__ x, float* __restrict__ out) {
    __shared__ float lds[WPB * OSTRIDE];  // 16640 B

    const int tid  = threadIdx.x;
    const int role = tid >> 6;           // wave index: 0..3 (wave-uniform)
    const int k    = tid & 63;           // window within block

    // Bijective XCD swizzle.
    const int bid = (int)blockIdx.x;
    const int blk = (bid % NXCD) * CPX + bid / NXCD;
    const int n = blk * WPB + k;

    const int w  = n % nW;
    const int tt = n / nW;
    const int h  = tt % nH;
    const int bc = tt / nH;  // b*C + c

    const float* xp = x + ((size_t)bc * H + (size_t)h * SH) * W + (size_t)w * SW;

    float* slot = &lds[k * OSTRIDE];

#define LOADROW(dst, ri)                                                              \
    {                                                                                 \
        const float4 lo_ = *reinterpret_cast<const float4*>(xp + (size_t)(ri)*W);     \
        const float4 hi_ = *reinterpret_cast<const float4*>(xp + (size_t)(ri)*W + 4); \
        dst[0]=lo_.x; dst[1]=lo_.y; dst[2]=lo_.z; dst[3]=lo_.w;                       \
        dst[4]=hi_.x; dst[5]=hi_.y; dst[6]=hi_.z; dst[7]=hi_.w;                       \
    }

    // acc[dx] += A[j+OX] * B[j], static j-guards (48 FMA).
#define FMABLK(ACC, AROW, BROW)                                                       \
    {                                                                                 \
        _Pragma("unroll")                                                             \
        for (int dx = 0; dx < 8; ++dx) {                                              \
            const int OX = dx - 4;                                                    \
            _Pragma("unroll")                                                         \
            for (int j = 0; j < 8; ++j) {                                             \
                if (j + OX < 0 || j + OX >= 8) continue; /* static DCE */             \
                ACC[dx] = fmaf(AROW[j + OX], BROW[j], ACC[dx]);                       \
            }                                                                         \
        }                                                                             \
    }

    // folded cell (4+d, 0): CC += sum_{j=0..3} B[j] * A[j+4]
#define CELLF(CC, AROW, BROW)                                                         \
    {                                                                                 \
        CC = fmaf(BROW[0], AROW[4], CC); CC = fmaf(BROW[1], AROW[5], CC);             \
        CC = fmaf(BROW[2], AROW[6], CC); CC = fmaf(BROW[3], AROW[7], CC);             \
    }

    if (role == 0) {
        // ---- W0: d=0 (dy=4) + d=4 (dy=0). cur + reloaded aux(r-4). ----
        float a0[8], a4[8];
#pragma unroll
        for (int dx = 0; dx < 8; ++dx) { a0[dx] = 0.f; a4[dx] = 0.f; }
        float cur[8], aux[8];
#pragma unroll
        for (int r = 0; r < 8; ++r) {
            LOADROW(cur, r)
            FMABLK(a0, cur, cur)                       // d=0: A=B=rows[r]
            if (r >= 4) {
                LOADROW(aux, r - 4)                    // L1-hot (self, 4 steps ago)
                FMABLK(a4, aux, cur)                   // d=4: A=rows[r-4]
            }
            __builtin_amdgcn_sched_barrier(0);
        }
        // stage: dy=0 row (a4), dy=4 row (a0)
        *reinterpret_cast<float4*>(slot + 0)  = make_float4(a4[0], a4[1], a4[2], a4[3]);
        *reinterpret_cast<float4*>(slot + 4)  = make_float4(a4[4], a4[5], a4[6], a4[7]);
        *reinterpret_cast<float4*>(slot + 32) = make_float4(a0[0], a0[1], a0[2], a0[3]);
        *reinterpret_cast<float4*>(slot + 36) = make_float4(a0[4], a0[5], a0[6], a0[7]);
    } else if (role == 1) {
        // ---- W1: d=1 (dy=3) + c50. 2-ring ping-pong. ----
        float a1[8]; float c50 = 0.f;
#pragma unroll
        for (int dx = 0; dx < 8; ++dx) a1[dx] = 0.f;
        float rr[2][8];
        LOADROW(rr[0], 0)
#pragma unroll
        for (int r = 1; r < 8; ++r) {
            LOADROW(rr[r & 1], r)
            FMABLK(a1, rr[(r - 1) & 1], rr[r & 1])     // A=rows[r-1], B=rows[r]
            CELLF(c50, rr[(r - 1) & 1], rr[r & 1])
            __builtin_amdgcn_sched_barrier(0);
        }
        // stage: dy=3 row + mirror row 5 ([5][0]=c50, [5][dx]=a1[8-dx])
        *reinterpret_cast<float4*>(slot + 24) = make_float4(a1[0], a1[1], a1[2], a1[3]);
        *reinterpret_cast<float4*>(slot + 28) = make_float4(a1[4], a1[5], a1[6], a1[7]);
        *reinterpret_cast<float4*>(slot + 40) = make_float4(c50,   a1[7], a1[6], a1[5]);
        *reinterpret_cast<float4*>(slot + 44) = make_float4(a1[4], a1[3], a1[2], a1[1]);
    } else if (role == 2) {
        // ---- W2: d=2 (dy=2) + c60. 3-ring. ----
        float a2[8]; float c60 = 0.f;
#pragma unroll
        for (int dx = 0; dx < 8; ++dx) a2[dx] = 0.f;
        float rr[3][8];
        LOADROW(rr[0], 0)
        LOADROW(rr[1], 1)
#pragma unroll
        for (int r = 2; r < 8; ++r) {
            LOADROW(rr[r % 3], r)                      // overwrites row r-3 (dead)
            FMABLK(a2, rr[(r - 2) % 3], rr[r % 3])     // A=rows[r-2], B=rows[r]
            CELLF(c60, rr[(r - 2) % 3], rr[r % 3])
            __builtin_amdgcn_sched_barrier(0);
        }
        // stage: dy=2 row + mirror row 6 ([6][0]=c60, [6][dx]=a2[8-dx])
        *reinterpret_cast<float4*>(slot + 16) = make_float4(a2[0], a2[1], a2[2], a2[3]);
        *reinterpret_cast<float4*>(slot + 20) = make_float4(a2[4], a2[5], a2[6], a2[7]);
        *reinterpret_cast<float4*>(slot + 48) = make_float4(c60,   a2[7], a2[6], a2[5]);
        *reinterpret_cast<float4*>(slot + 52) = make_float4(a2[4], a2[3], a2[2], a2[1]);
    } else {
        // ---- W3: d=3 (dy=1) + c70. 4-ring. ----
        float a3[8]; float c70 = 0.f;
#pragma unroll
        for (int dx = 0; dx < 8; ++dx) a3[dx] = 0.f;
        float rr[4][8];
        LOADROW(rr[0], 0)
        LOADROW(rr[1], 1)
        LOADROW(rr[2], 2)
#pragma unroll
        for (int r = 3; r < 8; ++r) {
            LOADROW(rr[r & 3], r)                      // overwrites row r-4 (dead)
            FMABLK(a3, rr[(r - 3) & 3], rr[r & 3])     // A=rows[r-3], B=rows[r]
            CELLF(c70, rr[(r - 3) & 3], rr[r & 3])
            __builtin_amdgcn_sched_barrier(0);
        }
        // stage: dy=1 row + mirror row 7 ([7][0]=c70, [7][dx]=a3[8-dx])
        *reinterpret_cast<float4*>(slot + 8)  = make_float4(a3[0], a3[1], a3[2], a3[3]);
        *reinterpret_cast<float4*>(slot + 12) = make_float4(a3[4], a3[5], a3[6], a3[7]);
        *reinterpret_cast<float4*>(slot + 56) = make_float4(c70,   a3[7], a3[6], a3[5]);
        *reinterpret_cast<float4*>(slot + 60) = make_float4(a3[4], a3[3], a3[2], a3[1]);
    }
#undef LOADROW
#undef FMABLK
#undef CELLF

    __syncthreads();

    // Flush: 64 windows x 16 float4 = 1024 slots, 4 per thread; each wave
    // store instruction covers 1KB contiguous (4 complete 256B regions).
    float* obase = out + (size_t)blk * WPB * 64;
#pragma unroll
    for (int kk = 0; kk < 4; ++kk) {
        const int flat4 = tid + kk * TPB;   // 0..1023
        const float4 v = *reinterpret_cast<const float4*>(
            &lds[(flat4 >> 4) * OSTRIDE + (flat4 & 15) * 4]);
        *reinterpret_cast<float4*>(obase + (size_t)flat4 * 4) = v;
    }
}

extern "C" void kernel_launch(void* const* d_in, const int* in_sizes, int n_in,
                              void* d_out, int out_size, void* d_ws, size_t ws_size,
                              hipStream_t stream) {
    const float* x = (const float*)d_in[0];
    float* out = (float*)d_out;

    local_autocorr_kernel<<<NBLK, TPB, 0, stream>>>(x, out);
}